// Round 8
// baseline (88.784 us; speedup 1.0000x reference)
//
#include <hip/hip_runtime.h>
#include <math.h>

#define BB 16
#define PP 2048
#define EPSF 1e-8f
#define SCALE (1.0f / (BB * PP))
#define NCHUNK 32
#define CHUNK 64   // cols per block
#define RPT 8      // rows per thread
#define REPEAT 8   // diagnostic amplification of the inner loop (identical math)

// ---------------- Kernel P: fused transform + pairwise partial min ----------
// grid = 1024 blocks: blk = db(5 bits: b*2+dir) << 5 | colchunk(5)
// block = 256 threads; each block: ALL 2048 rows x 64 cols (8 rows/thread).
// DIAGNOSTIC: inner j-loop repeated REPEAT times (results identical; reps kept
// live via opaque asm) so the kernel shows up in rocprof top-5 with counters.
// partial layout: partial[cc][db][row]  (32 x 32 x 2048 floats = 8 MB)
__global__ __launch_bounds__(256) void pairtrans_kernel(
    const float* __restrict__ R_t, const float* __restrict__ t_t,
    const float* __restrict__ R_p, const float* __restrict__ t_p,
    const float* __restrict__ mp,
    float* __restrict__ partial, float* __restrict__ out) {
  __shared__ float4 tile[CHUNK];  // 1 KB
  int blk = blockIdx.x;
  int t = threadIdx.x;
  if (blk == 0 && t == 0) *out = 0.0f;  // finish runs after -> safe
  int cc = blk & 31;
  int db = blk >> 5;  // 0..31
  int dir = db & 1;
  int b = db >> 1;
  const float* Rr = (dir ? R_p : R_t) + b * 9;
  const float* tr_ = (dir ? t_p : t_t) + b * 3;
  const float* Rc = (dir ? R_t : R_p) + b * 9;
  const float* tc_ = (dir ? t_t : t_p) + b * 3;

  // --- transform this block's column points -> LDS (col form: -2q, |q|^2) ---
  if (t < CHUNK) {
    int ci = (b << 11) + (cc << 6) + t;
    float x = mp[ci * 3], y = mp[ci * 3 + 1], z = mp[ci * 3 + 2];
    float qx = fmaf(Rc[0], x, fmaf(Rc[1], y, fmaf(Rc[2], z, tc_[0])));
    float qy = fmaf(Rc[3], x, fmaf(Rc[4], y, fmaf(Rc[5], z, tc_[1])));
    float qz = fmaf(Rc[6], x, fmaf(Rc[7], y, fmaf(Rc[8], z, tc_[2])));
    float qw = fmaf(qx, qx, fmaf(qy, qy, qz * qz));
    tile[t] = make_float4(-2.f * qx, -2.f * qy, -2.f * qz, qw);
  }

  // --- transform this thread's 8 rows -> registers (row form: p, |p|^2) ---
  float r0 = Rr[0], r1 = Rr[1], r2 = Rr[2], r3 = Rr[3], r4 = Rr[4],
        r5 = Rr[5], r6 = Rr[6], r7 = Rr[7], r8 = Rr[8];
  float t0 = tr_[0], t1 = tr_[1], t2 = tr_[2];
  float4 a[RPT];
#pragma unroll
  for (int k = 0; k < RPT; ++k) {
    int ri = (b << 11) + (k << 8) + t;
    float x = mp[ri * 3], y = mp[ri * 3 + 1], z = mp[ri * 3 + 2];
    float px = fmaf(r0, x, fmaf(r1, y, fmaf(r2, z, t0)));
    float py = fmaf(r3, x, fmaf(r4, y, fmaf(r5, z, t1)));
    float pz = fmaf(r6, x, fmaf(r7, y, fmaf(r8, z, t2)));
    a[k] = make_float4(px, py, pz, fmaf(px, px, fmaf(py, py, pz * pz)));
  }
  __syncthreads();

  float m[RPT];
#pragma unroll 1
  for (int rep = 0; rep < REPEAT; ++rep) {
    // opaque identity on inputs: defeats CSE across reps (values unchanged)
#pragma unroll
    for (int k = 0; k < RPT; ++k) {
      asm volatile("" : "+v"(a[k].x), "+v"(a[k].y), "+v"(a[k].z), "+v"(a[k].w));
    }
#pragma unroll
    for (int k = 0; k < RPT; ++k) m[k] = 3.0e38f;

#pragma unroll 4
    for (int j = 0; j < CHUNK; j += 2) {
      float4 q0 = tile[j];
      float4 q1 = tile[j + 1];
#pragma unroll
      for (int k = 0; k < RPT; ++k) {
        float s0 = fmaf(a[k].x, q0.x, fmaf(a[k].y, q0.y, fmaf(a[k].z, q0.z, q0.w)));
        float s1 = fmaf(a[k].x, q1.x, fmaf(a[k].y, q1.y, fmaf(a[k].z, q1.z, q1.w)));
        m[k] = fminf(fminf(m[k], s0), s1);  // -> v_min3_f32
      }
    }
    // observe outputs: defeats DCE of reps 0..REPEAT-2
#pragma unroll
    for (int k = 0; k < RPT; ++k) asm volatile("" : "+v"(m[k]));
  }

  float* pp = partial + (cc << 16) + (db << 11) + t;
#pragma unroll
  for (int k = 0; k < RPT; ++k) pp[k << 8] = m[k] + a[k].w;
}

// ---------------- Kernel F: reduce chunks + sqrt + mean ----------------
__global__ __launch_bounds__(256) void finish_kernel(
    const float* __restrict__ partial, float* __restrict__ out) {
  int idx = blockIdx.x * 256 + threadIdx.x;  // 0..65535 = db*2048+row
  float v = partial[idx];
#pragma unroll
  for (int c = 1; c < NCHUNK; ++c) v = fminf(v, partial[(c << 16) + idx]);
  v = fmaxf(v, 0.0f);  // guard tiny negative from cancellation
  float s = sqrtf(v + EPSF) * SCALE;
  for (int off = 32; off; off >>= 1) s += __shfl_down(s, off, 64);
  __shared__ float wsum[4];
  if ((threadIdx.x & 63) == 0) wsum[threadIdx.x >> 6] = s;
  __syncthreads();
  if (threadIdx.x == 0) atomicAdd(out, wsum[0] + wsum[1] + wsum[2] + wsum[3]);
}

// ---------------- Fallback (tiny ws): self-contained, no scratch ------------
__global__ __launch_bounds__(256) void fallback_kernel(
    const float* __restrict__ R_t, const float* __restrict__ t_t,
    const float* __restrict__ R_p, const float* __restrict__ t_p,
    const float* __restrict__ mp, float* __restrict__ out) {
  __shared__ float4 lds[PP];  // 32 KB
  int blk = blockIdx.x;
  int rc  = blk & 7;
  int dir = (blk >> 3) & 1;
  int b   = blk >> 4;
  const float* Rr = (dir ? R_p : R_t) + b * 9;
  const float* tr_ = (dir ? t_p : t_t) + b * 3;
  const float* Rc = (dir ? R_t : R_p) + b * 9;
  const float* tcp = (dir ? t_t : t_p) + b * 3;
  float c0 = Rc[0], c1 = Rc[1], c2 = Rc[2], c3 = Rc[3], c4 = Rc[4],
        c5 = Rc[5], c6 = Rc[6], c7 = Rc[7], c8 = Rc[8];
  float tc0 = tcp[0], tc1 = tcp[1], tc2 = tcp[2];
  for (int j = threadIdx.x; j < PP; j += 256) {
    int gi = (b * PP + j) * 3;
    float x = mp[gi], y = mp[gi + 1], z = mp[gi + 2];
    float4 q;
    q.x = fmaf(c0, x, fmaf(c1, y, fmaf(c2, z, tc0)));
    q.y = fmaf(c3, x, fmaf(c4, y, fmaf(c5, z, tc1)));
    q.z = fmaf(c6, x, fmaf(c7, y, fmaf(c8, z, tc2)));
    q.w = 0.f;
    lds[j] = q;
  }
  __syncthreads();
  int row = rc * 256 + threadIdx.x;
  int gi = (b * PP + row) * 3;
  float x = mp[gi], y = mp[gi + 1], z = mp[gi + 2];
  float ax = fmaf(Rr[0], x, fmaf(Rr[1], y, fmaf(Rr[2], z, tr_[0])));
  float ay = fmaf(Rr[3], x, fmaf(Rr[4], y, fmaf(Rr[5], z, tr_[1])));
  float az = fmaf(Rr[6], x, fmaf(Rr[7], y, fmaf(Rr[8], z, tr_[2])));
  float m = 3.4e38f;
#pragma unroll 8
  for (int j = 0; j < PP; ++j) {
    float4 q = lds[j];
    float dx = ax - q.x, dy = ay - q.y, dz = az - q.z;
    float d = fmaf(dx, dx, fmaf(dy, dy, dz * dz));
    m = fminf(m, d);
  }
  float v = sqrtf(m + EPSF) * SCALE;
  for (int off = 32; off; off >>= 1) v += __shfl_down(v, off, 64);
  __shared__ float wsum[4];
  if ((threadIdx.x & 63) == 0) wsum[threadIdx.x >> 6] = v;
  __syncthreads();
  if (threadIdx.x == 0) atomicAdd(out, wsum[0] + wsum[1] + wsum[2] + wsum[3]);
}

extern "C" void kernel_launch(void* const* d_in, const int* in_sizes, int n_in,
                              void* d_out, int out_size, void* d_ws, size_t ws_size,
                              hipStream_t stream) {
  const float* R_t = (const float*)d_in[0];
  const float* t_t = (const float*)d_in[1];
  const float* R_p = (const float*)d_in[2];
  const float* t_p = (const float*)d_in[3];
  const float* mp  = (const float*)d_in[4];
  float* out = (float*)d_out;

  size_t need = (size_t)NCHUNK * 2 * BB * PP * sizeof(float);  // 8 MB
  if (ws_size >= need) {
    float* partial = (float*)d_ws;
    pairtrans_kernel<<<1024, 256, 0, stream>>>(R_t, t_t, R_p, t_p, mp, partial, out);
    finish_kernel<<<256, 256, 0, stream>>>(partial, out);
  } else {
    hipMemsetAsync(d_out, 0, sizeof(float), stream);
    fallback_kernel<<<256, 256, 0, stream>>>(R_t, t_t, R_p, t_p, mp, out);
  }
}

// Round 9
// 25.350 us; speedup vs baseline: 3.5023x; 3.5023x over previous
//
#include <hip/hip_runtime.h>
#include <math.h>

#define BB 16
#define PP 2048
#define EPSF 1e-8f
#define SCALE (1.0f / (BB * PP))
#define NCHUNK 32   // 32 col-chunks of 64 cols
#define RPT 16      // rows per thread

typedef float f2 __attribute__((ext_vector_type(2)));

// packed fp32 fma: d = a*b + c on both 32-bit halves (gfx90a+/gfx950 VOP3P)
static __device__ __forceinline__ f2 pkfma(f2 a, f2 b, f2 c) {
  f2 d;
  asm("v_pk_fma_f32 %0, %1, %2, %3" : "=v"(d) : "v"(a), "v"(b), "v"(c));
  return d;
}

// ---------------- Kernel P: fused transform + pairwise partial min ----------
// grid = 512: blk = db(5b) * 16 + sc(4b). block = 256 = two halves of 128 thr.
// Half h covers col-chunk cc = sc*2+h (64 cols); all 2048 rows, 16 rows/thread.
// Inner: packed rows (2 per f2), packed cols (2 per LDS f2), diagonal trick:
//   d1 = (s(r0,c0), s(r1,c1)),  d2 = (s(r0,c1), s(r1,c0))  -> 6 pk_fma + 2 min3
// partial layout: partial[cc][db][row]  (32 x 32 x 2048 floats = 8 MB)
__global__ __launch_bounds__(256) void pairtrans_kernel(
    const float* __restrict__ R_t, const float* __restrict__ t_t,
    const float* __restrict__ R_p, const float* __restrict__ t_p,
    const float* __restrict__ mp,
    float* __restrict__ partial, float* __restrict__ out) {
  __shared__ f2 Qx[2][32], Qy[2][32], Qz[2][32], Qw[2][32];  // 2 KB
  int blk = blockIdx.x;
  int t = threadIdx.x;
  if (blk == 0 && t == 0) *out = 0.0f;  // finish runs after -> safe
  int sc = blk & 15;
  int db = blk >> 4;  // 0..31
  int dir = db & 1;
  int b = db >> 1;
  int h = t >> 7;        // half 0/1
  int tl = t & 127;
  int cc = (sc << 1) | h;  // col chunk 0..31
  const float* Rr = (dir ? R_p : R_t) + b * 9;
  const float* tr_ = (dir ? t_p : t_t) + b * 3;
  const float* Rc = (dir ? R_t : R_p) + b * 9;
  const float* tc_ = (dir ? t_t : t_p) + b * 3;

  // --- transform 64 cols of this half -> LDS (col form: -2q, |q|^2) ---
  if (tl < 64) {
    int ci = (b << 11) + (cc << 6) + tl;
    float x = mp[ci * 3], y = mp[ci * 3 + 1], z = mp[ci * 3 + 2];
    float qx = fmaf(Rc[0], x, fmaf(Rc[1], y, fmaf(Rc[2], z, tc_[0])));
    float qy = fmaf(Rc[3], x, fmaf(Rc[4], y, fmaf(Rc[5], z, tc_[1])));
    float qz = fmaf(Rc[6], x, fmaf(Rc[7], y, fmaf(Rc[8], z, tc_[2])));
    float qw = fmaf(qx, qx, fmaf(qy, qy, qz * qz));
    ((float*)&Qx[h][0])[tl] = -2.f * qx;
    ((float*)&Qy[h][0])[tl] = -2.f * qy;
    ((float*)&Qz[h][0])[tl] = -2.f * qz;
    ((float*)&Qw[h][0])[tl] = qw;
  }

  // --- transform this thread's 16 rows -> packed row-pair registers ---
  float r0 = Rr[0], r1 = Rr[1], r2 = Rr[2], r3 = Rr[3], r4 = Rr[4],
        r5 = Rr[5], r6 = Rr[6], r7 = Rr[7], r8 = Rr[8];
  float t0 = tr_[0], t1 = tr_[1], t2 = tr_[2];
  f2 ax[RPT / 2], ay[RPT / 2], az[RPT / 2], aw[RPT / 2];
#pragma unroll
  for (int k = 0; k < RPT; ++k) {
    int ri = (b << 11) + (k << 7) + tl;
    float x = mp[ri * 3], y = mp[ri * 3 + 1], z = mp[ri * 3 + 2];
    float px = fmaf(r0, x, fmaf(r1, y, fmaf(r2, z, t0)));
    float py = fmaf(r3, x, fmaf(r4, y, fmaf(r5, z, t1)));
    float pz = fmaf(r6, x, fmaf(r7, y, fmaf(r8, z, t2)));
    float pw = fmaf(px, px, fmaf(py, py, pz * pz));
    if (k & 1) {
      ax[k >> 1].y = px; ay[k >> 1].y = py; az[k >> 1].y = pz; aw[k >> 1].y = pw;
    } else {
      ax[k >> 1].x = px; ay[k >> 1].x = py; az[k >> 1].x = pz; aw[k >> 1].x = pw;
    }
  }
  __syncthreads();

  float m[RPT];
#pragma unroll
  for (int k = 0; k < RPT; ++k) m[k] = 3.0e38f;

  const f2* qx = &Qx[h][0];
  const f2* qy = &Qy[h][0];
  const f2* qz = &Qz[h][0];
  const f2* qw = &Qw[h][0];

#pragma unroll 2
  for (int jp = 0; jp < 32; ++jp) {
    f2 X = qx[jp], Y = qy[jp], Z = qz[jp], W = qw[jp];
    f2 Xs, Ys, Zs, Ws;
    Xs.x = X.y; Xs.y = X.x;
    Ys.x = Y.y; Ys.y = Y.x;
    Zs.x = Z.y; Zs.y = Z.x;
    Ws.x = W.y; Ws.y = W.x;
#pragma unroll
    for (int kk = 0; kk < RPT / 2; ++kk) {
      f2 d1 = pkfma(ax[kk], X, pkfma(ay[kk], Y, pkfma(az[kk], Z, W)));
      f2 d2 = pkfma(ax[kk], Xs, pkfma(ay[kk], Ys, pkfma(az[kk], Zs, Ws)));
      m[2 * kk]     = fminf(fminf(m[2 * kk], d1.x), d2.x);      // v_min3
      m[2 * kk + 1] = fminf(fminf(m[2 * kk + 1], d1.y), d2.y);  // v_min3
    }
  }

  float* pp = partial + (cc << 16) + (db << 11) + tl;
#pragma unroll
  for (int kk = 0; kk < RPT / 2; ++kk) {
    pp[(2 * kk) << 7]     = m[2 * kk] + aw[kk].x;
    pp[(2 * kk + 1) << 7] = m[2 * kk + 1] + aw[kk].y;
  }
}

// ---------------- Kernel F: reduce chunks + sqrt + mean ----------------
__global__ __launch_bounds__(256) void finish_kernel(
    const float* __restrict__ partial, float* __restrict__ out) {
  int idx = blockIdx.x * 256 + threadIdx.x;  // 0..65535 = db*2048+row
  float v = partial[idx];
#pragma unroll
  for (int c = 1; c < NCHUNK; ++c) v = fminf(v, partial[(c << 16) + idx]);
  v = fmaxf(v, 0.0f);  // guard tiny negative from cancellation
  float s = sqrtf(v + EPSF) * SCALE;
  for (int off = 32; off; off >>= 1) s += __shfl_down(s, off, 64);
  __shared__ float wsum[4];
  if ((threadIdx.x & 63) == 0) wsum[threadIdx.x >> 6] = s;
  __syncthreads();
  if (threadIdx.x == 0) atomicAdd(out, wsum[0] + wsum[1] + wsum[2] + wsum[3]);
}

// ---------------- Fallback (tiny ws): self-contained, no scratch ------------
__global__ __launch_bounds__(256) void fallback_kernel(
    const float* __restrict__ R_t, const float* __restrict__ t_t,
    const float* __restrict__ R_p, const float* __restrict__ t_p,
    const float* __restrict__ mp, float* __restrict__ out) {
  __shared__ float4 lds[PP];  // 32 KB
  int blk = blockIdx.x;
  int rc  = blk & 7;
  int dir = (blk >> 3) & 1;
  int b   = blk >> 4;
  const float* Rr = (dir ? R_p : R_t) + b * 9;
  const float* tr_ = (dir ? t_p : t_t) + b * 3;
  const float* Rc = (dir ? R_t : R_p) + b * 9;
  const float* tcp = (dir ? t_t : t_p) + b * 3;
  float c0 = Rc[0], c1 = Rc[1], c2 = Rc[2], c3 = Rc[3], c4 = Rc[4],
        c5 = Rc[5], c6 = Rc[6], c7 = Rc[7], c8 = Rc[8];
  float tc0 = tcp[0], tc1 = tcp[1], tc2 = tcp[2];
  for (int j = threadIdx.x; j < PP; j += 256) {
    int gi = (b * PP + j) * 3;
    float x = mp[gi], y = mp[gi + 1], z = mp[gi + 2];
    float4 q;
    q.x = fmaf(c0, x, fmaf(c1, y, fmaf(c2, z, tc0)));
    q.y = fmaf(c3, x, fmaf(c4, y, fmaf(c5, z, tc1)));
    q.z = fmaf(c6, x, fmaf(c7, y, fmaf(c8, z, tc2)));
    q.w = 0.f;
    lds[j] = q;
  }
  __syncthreads();
  int row = rc * 256 + threadIdx.x;
  int gi = (b * PP + row) * 3;
  float x = mp[gi], y = mp[gi + 1], z = mp[gi + 2];
  float ax = fmaf(Rr[0], x, fmaf(Rr[1], y, fmaf(Rr[2], z, tr_[0])));
  float ay = fmaf(Rr[3], x, fmaf(Rr[4], y, fmaf(Rr[5], z, tr_[1])));
  float az = fmaf(Rr[6], x, fmaf(Rr[7], y, fmaf(Rr[8], z, tr_[2])));
  float m = 3.4e38f;
#pragma unroll 8
  for (int j = 0; j < PP; ++j) {
    float4 q = lds[j];
    float dx = ax - q.x, dy = ay - q.y, dz = az - q.z;
    float d = fmaf(dx, dx, fmaf(dy, dy, dz * dz));
    m = fminf(m, d);
  }
  float v = sqrtf(m + EPSF) * SCALE;
  for (int off = 32; off; off >>= 1) v += __shfl_down(v, off, 64);
  __shared__ float wsum[4];
  if ((threadIdx.x & 63) == 0) wsum[threadIdx.x >> 6] = v;
  __syncthreads();
  if (threadIdx.x == 0) atomicAdd(out, wsum[0] + wsum[1] + wsum[2] + wsum[3]);
}

extern "C" void kernel_launch(void* const* d_in, const int* in_sizes, int n_in,
                              void* d_out, int out_size, void* d_ws, size_t ws_size,
                              hipStream_t stream) {
  const float* R_t = (const float*)d_in[0];
  const float* t_t = (const float*)d_in[1];
  const float* R_p = (const float*)d_in[2];
  const float* t_p = (const float*)d_in[3];
  const float* mp  = (const float*)d_in[4];
  float* out = (float*)d_out;

  size_t need = (size_t)NCHUNK * 2 * BB * PP * sizeof(float);  // 8 MB
  if (ws_size >= need) {
    float* partial = (float*)d_ws;
    pairtrans_kernel<<<512, 256, 0, stream>>>(R_t, t_t, R_p, t_p, mp, partial, out);
    finish_kernel<<<256, 256, 0, stream>>>(partial, out);
  } else {
    hipMemsetAsync(d_out, 0, sizeof(float), stream);
    fallback_kernel<<<256, 256, 0, stream>>>(R_t, t_t, R_p, t_p, mp, out);
  }
}